// Round 1
// baseline (50.633 us; speedup 1.0000x reference)
//
#include <hip/hip_runtime.h>
#include <math.h>

#define E_CNT 1999
#define N_PTS 2000
#define B_CNT 8
#define M_CNT (2*E_CNT)                    // 3998 combined signed edges
#define TILE 256
#define NTILES ((M_CNT + TILE - 1)/TILE)   // 16
#define NTP ((NTILES*(NTILES+1))/2)        // 136 upper-triangle tile pairs
#define WS_STRIDE 32                       // pad accumulators to 128B

#define CEXP  (-5.7707801635558535f)       // -4 * log2(e)
#define NEG2C (11.541560327111707f)        // -2 * CEXP

// Compute combined-edge p data for sample b.
// p < E_CNT: X-edge (output+template), weight +l. Else: target edge, weight -l.
__device__ __forceinline__ void compute_edge(
    const float* __restrict__ outp, const float* __restrict__ tgtp,
    const float* __restrict__ tmpl, int b, int p,
    float& cx, float& cy, float& cz,
    float& ux, float& uy, float& uz, float& w, float& Bc)
{
    float ax, ay, az, bx, by, bz;
    if (p < E_CNT) {
        const float* o0 = outp + ((size_t)b * N_PTS + p) * 3;
        const float* t0 = tmpl + (size_t)p * 3;
        ax = o0[0] + t0[0]; ay = o0[1] + t0[1]; az = o0[2] + t0[2];
        bx = o0[3] + t0[3]; by = o0[4] + t0[4]; bz = o0[5] + t0[5];
    } else {
        int e = p - E_CNT;
        const float* g0 = tgtp + ((size_t)b * N_PTS + e) * 3;
        ax = g0[0]; ay = g0[1]; az = g0[2];
        bx = g0[3]; by = g0[4]; bz = g0[5];
    }
    cx = 0.5f * (ax + bx); cy = 0.5f * (ay + by); cz = 0.5f * (az + bz);
    float tx = bx - ax, ty = by - ay, tz = bz - az;
    float l = sqrtf(tx * tx + ty * ty + tz * tz + 1e-12f);
    float rl = 1.0f / l;
    ux = tx * rl; uy = ty * rl; uz = tz * rl;
    w = (p < E_CNT) ? l : -l;
    Bc = CEXP * (cx * cx + cy * cy + cz * cz);
}

// Per-edge terms: diagonal (l_X^2 + l_Y^2) + SRNF_W * |q_X - q_T|^2
__global__ __launch_bounds__(256) void aux_kernel(
    const float* __restrict__ outp, const float* __restrict__ tgtp,
    const float* __restrict__ tmpl, float* __restrict__ acc)
{
    int b = blockIdx.x >> 3;                       // 8 blocks per sample
    int e = ((blockIdx.x & 7) << 8) + threadIdx.x; // 8*256=2048 >= 1999
    float val = 0.f;
    if (e < E_CNT) {
        const float* o0 = outp + ((size_t)b * N_PTS + e) * 3;
        const float* t0 = tmpl + (size_t)e * 3;
        float x0 = o0[0] + t0[0], y0 = o0[1] + t0[1], z0 = o0[2] + t0[2];
        float x1 = o0[3] + t0[3], y1 = o0[4] + t0[4], z1 = o0[5] + t0[5];
        float txX = x1 - x0, tyX = y1 - y0, tzX = z1 - z0;
        float lX = sqrtf(txX * txX + tyX * tyX + tzX * tzX + 1e-12f);

        const float* g0 = tgtp + ((size_t)b * N_PTS + e) * 3;
        float txY = g0[3] - g0[0], tyY = g0[4] - g0[1], tzY = g0[5] - g0[2];
        float lY = sqrtf(txY * txY + tyY * tyY + tzY * tzY + 1e-12f);

        float txT = t0[3] - t0[0], tyT = t0[4] - t0[1], tzT = t0[5] - t0[2];
        float lT = sqrtf(txT * txT + tyT * tyT + tzT * tzT + 1e-12f);

        // srvf q = u*sqrt(l) = t / sqrt(l)
        float rX = rsqrtf(lX), rT = rsqrtf(lT);
        float dqx = txX * rX - txT * rT;
        float dqy = tyX * rX - tyT * rT;
        float dqz = tzX * rX - tzT * rT;
        val = lX * lX + lY * lY + 1e-7f * (dqx * dqx + dqy * dqy + dqz * dqz);
    }
    // block reduce
    for (int off = 32; off; off >>= 1) val += __shfl_down(val, off);
    __shared__ float red[4];
    int lane = threadIdx.x & 63, wid = threadIdx.x >> 6;
    if (lane == 0) red[wid] = val;
    __syncthreads();
    if (threadIdx.x == 0)
        atomicAdd(&acc[b * WS_STRIDE], (red[0] + red[1]) + (red[2] + red[3]));
}

// Strict-upper-triangle pair sum over combined signed edges; result *2.
__global__ __launch_bounds__(256) void pair_kernel(
    const float* __restrict__ outp, const float* __restrict__ tgtp,
    const float* __restrict__ tmpl, float* __restrict__ acc)
{
    __shared__ float4 sC[TILE];  // cx, cy, cz, B=C*|c|^2
    __shared__ float4 sU[TILE];  // ux, uy, uz, w (signed length)

    int blk = blockIdx.x;
    int b = blk / NTP;
    int t = blk % NTP;
    int rt = 0, rem = t;
    while (rem >= NTILES - rt) { rem -= NTILES - rt; ++rt; }
    int ct = rt + rem;

    int tid = threadIdx.x;

    // stage column tile into LDS
    {
        float ccx = 0, ccy = 0, ccz = 0, cux = 0, cuy = 0, cuz = 0, cw = 0, cB = 0;
        int cj = ct * TILE + tid;
        if (cj < M_CNT)
            compute_edge(outp, tgtp, tmpl, b, cj, ccx, ccy, ccz, cux, cuy, cuz, cw, cB);
        sC[tid] = make_float4(ccx, ccy, ccz, cB);
        sU[tid] = make_float4(cux, cuy, cuz, cw);
    }

    // row edge in registers
    float rcx = 0, rcy = 0, rcz = 0, rux = 0, ruy = 0, ruz = 0, rw = 0, rA = 0;
    int ri = rt * TILE + tid;
    if (ri < M_CNT)
        compute_edge(outp, tgtp, tmpl, b, ri, rcx, rcy, rcz, rux, ruy, ruz, rw, rA);

    __syncthreads();

    float accv = 0.f;
    if (rt != ct) {
        #pragma unroll 4
        for (int j = 0; j < TILE; ++j) {
            float4 c4 = sC[j];
            float4 u4 = sU[j];
            float dc  = rcx * c4.x + rcy * c4.y + rcz * c4.z;
            float arg = fmaf(NEG2C, dc, rA + c4.w);
            float K   = __builtin_amdgcn_exp2f(arg);
            float du  = rux * u4.x + ruy * u4.y + ruz * u4.z;
            float t2  = K * du * du;
            accv = fmaf(t2, u4.w, accv);
        }
    } else {
        #pragma unroll 4
        for (int j = 0; j < TILE; ++j) {
            float4 c4 = sC[j];
            float4 u4 = sU[j];
            float wj  = (j > tid) ? u4.w : 0.f;   // strict upper
            float dc  = rcx * c4.x + rcy * c4.y + rcz * c4.z;
            float arg = fmaf(NEG2C, dc, rA + c4.w);
            float K   = __builtin_amdgcn_exp2f(arg);
            float du  = rux * u4.x + ruy * u4.y + ruz * u4.z;
            float t2  = K * du * du;
            accv = fmaf(t2, wj, accv);
        }
    }

    float thr = accv * rw;
    for (int off = 32; off; off >>= 1) thr += __shfl_down(thr, off);
    __shared__ float red[4];
    int lane = tid & 63, wid = tid >> 6;
    if (lane == 0) red[wid] = thr;
    __syncthreads();
    if (tid == 0)
        atomicAdd(&acc[b * WS_STRIDE], 2.0f * ((red[0] + red[1]) + (red[2] + red[3])));
}

__global__ void final_kernel(const float* __restrict__ acc, float* __restrict__ outv)
{
    float s = 0.f;
    for (int b = 0; b < B_CNT; ++b) s += acc[b * WS_STRIDE];
    outv[0] = 0.125f * s;
}

extern "C" void kernel_launch(void* const* d_in, const int* in_sizes, int n_in,
                              void* d_out, int out_size, void* d_ws, size_t ws_size,
                              hipStream_t stream)
{
    const float* outp = (const float*)d_in[0];  // (8,2000,3) f32
    const float* tgtp = (const float*)d_in[1];  // (8,2000,3) f32
    // d_in[2] = tedges (int32, arange pairs) -- unused, structure known
    const float* tmpl = (const float*)d_in[3];  // (2000,3) f32
    // d_in[4] = edges (int32) -- unused
    float* acc = (float*)d_ws;

    hipMemsetAsync(d_ws, 0, B_CNT * WS_STRIDE * sizeof(float), stream);
    aux_kernel<<<B_CNT * 8, 256, 0, stream>>>(outp, tgtp, tmpl, acc);
    pair_kernel<<<B_CNT * NTP, 256, 0, stream>>>(outp, tgtp, tmpl, acc);
    final_kernel<<<1, 1, 0, stream>>>(acc, (float*)d_out);
}

// Round 2
// 48.401 us; speedup vs baseline: 1.0461x; 1.0461x over previous
//
#include <hip/hip_runtime.h>
#include <math.h>

#define E_CNT 1999
#define N_PTS 2000
#define B_CNT 8
#define M_CNT (2*E_CNT)                    // 3998 combined signed edges
#define MPAD 4096                          // padded edge count (zero-filled)
#define WS_STRIDE 32                       // acc padded to 128B per sample
#define NTILES 16                          // 256-row tiles over MPAD
#define NTP 136                            // upper-triangle tile pairs
#define NQ 4                               // 64-col quarters per tile
#define BLOCKS_PER_B (NTP*NQ)              // 544

#define CEXP  (-5.7707801635558535f)       // -4 * log2(e)
#define NEG2C (11.541560327111707f)        // -2 * CEXP

// Precompute combined-edge data for all samples to global scratch:
//   ecu[2*(b*MPAD+p)+0] = (cx, cy, cz, CEXP*|c|^2)
//   ecu[2*(b*MPAD+p)+1] = (ux, uy, uz, w)   w = +l (X edge) or -l (target edge)
// Also accumulates per-sample diagonal (sum l^2 over both measures) + SRNF term.
__global__ __launch_bounds__(256) void pre_kernel(
    const float* __restrict__ outp, const float* __restrict__ tgtp,
    const float* __restrict__ tmpl, float4* __restrict__ ecu,
    float* __restrict__ acc)
{
    int b = blockIdx.x >> 4;
    int p = ((blockIdx.x & 15) << 8) + threadIdx.x;   // 0..4095

    float val = 0.f;
    float4 C = make_float4(0.f, 0.f, 0.f, 0.f);
    float4 U = make_float4(0.f, 0.f, 0.f, 0.f);

    if (p < M_CNT) {
        float ax, ay, az, bx, by, bz;
        bool isX = (p < E_CNT);
        if (isX) {
            const float* o0 = outp + ((size_t)b * N_PTS + p) * 3;
            const float* t0 = tmpl + (size_t)p * 3;
            ax = o0[0] + t0[0]; ay = o0[1] + t0[1]; az = o0[2] + t0[2];
            bx = o0[3] + t0[3]; by = o0[4] + t0[4]; bz = o0[5] + t0[5];
        } else {
            int e = p - E_CNT;
            const float* g0 = tgtp + ((size_t)b * N_PTS + e) * 3;
            ax = g0[0]; ay = g0[1]; az = g0[2];
            bx = g0[3]; by = g0[4]; bz = g0[5];
        }
        float cx = 0.5f * (ax + bx), cy = 0.5f * (ay + by), cz = 0.5f * (az + bz);
        float tx = bx - ax, ty = by - ay, tz = bz - az;
        float l = sqrtf(tx * tx + ty * ty + tz * tz + 1e-12f);
        float rl = 1.0f / l;
        float w = isX ? l : -l;
        C = make_float4(cx, cy, cz, CEXP * (cx * cx + cy * cy + cz * cz));
        U = make_float4(tx * rl, ty * rl, tz * rl, w);
        val = l * l;
        if (isX) {
            const float* t0 = tmpl + (size_t)p * 3;
            float txT = t0[3] - t0[0], tyT = t0[4] - t0[1], tzT = t0[5] - t0[2];
            float lT = sqrtf(txT * txT + tyT * tyT + tzT * tzT + 1e-12f);
            float rX = rsqrtf(l), rT = rsqrtf(lT);
            float dqx = tx * rX - txT * rT;
            float dqy = ty * rX - tyT * rT;
            float dqz = tz * rX - tzT * rT;
            val += 1e-7f * (dqx * dqx + dqy * dqy + dqz * dqz);
        }
    }
    size_t base = 2 * ((size_t)b * MPAD + p);
    ecu[base]     = C;
    ecu[base + 1] = U;

    for (int off = 32; off; off >>= 1) val += __shfl_down(val, off);
    __shared__ float red[4];
    int lane = threadIdx.x & 63, wid = threadIdx.x >> 6;
    if (lane == 0) red[wid] = val;
    __syncthreads();
    if (threadIdx.x == 0)
        atomicAdd(&acc[b * WS_STRIDE], (red[0] + red[1]) + (red[2] + red[3]));
}

// Strict-upper-triangle pair sum. 64-thread blocks, R=4 rows/lane,
// 64-col chunks. Column data via wave-uniform (scalar) loads.
__global__ __launch_bounds__(64) void pair_kernel(
    const float4* __restrict__ ecu, float* __restrict__ acc)
{
    int id = blockIdx.x;
    int b = id / BLOCKS_PER_B;
    int r = id % BLOCKS_PER_B;
    int t = r >> 2, q = r & 3;
    int rt = 0, rem = t;
    while (rem >= NTILES - rt) { rem -= NTILES - rt; ++rt; }
    int ct = rt + rem;

    int lane = threadIdx.x;
    const float4* __restrict__ eb = ecu + (size_t)b * MPAD * 2;

    float4 rc[4], ru[4];
    int   ri[4];
    #pragma unroll
    for (int k = 0; k < 4; ++k) {
        int i = rt * 256 + lane + 64 * k;
        ri[k] = i;
        rc[k] = eb[2 * i];
        ru[k] = eb[2 * i + 1];
    }

    float av[4] = {0.f, 0.f, 0.f, 0.f};
    int j0 = ct * 256 + q * 64;

    if (rt != ct) {
        #pragma unroll 4
        for (int jj = 0; jj < 64; ++jj) {
            int j = j0 + jj;
            float4 cc = eb[2 * j];       // wave-uniform -> s_load
            float4 cu = eb[2 * j + 1];
            #pragma unroll
            for (int k = 0; k < 4; ++k) {
                float dc  = rc[k].x * cc.x + rc[k].y * cc.y + rc[k].z * cc.z;
                float arg = fmaf(NEG2C, dc, rc[k].w + cc.w);
                float K   = __builtin_amdgcn_exp2f(arg);
                float du  = ru[k].x * cu.x + ru[k].y * cu.y + ru[k].z * cu.z;
                av[k] = fmaf(K * du * du, cu.w, av[k]);
            }
        }
    } else {
        #pragma unroll 4
        for (int jj = 0; jj < 64; ++jj) {
            int j = j0 + jj;
            float4 cc = eb[2 * j];
            float4 cu = eb[2 * j + 1];
            #pragma unroll
            for (int k = 0; k < 4; ++k) {
                float wj  = (j > ri[k]) ? cu.w : 0.f;   // strict upper
                float dc  = rc[k].x * cc.x + rc[k].y * cc.y + rc[k].z * cc.z;
                float arg = fmaf(NEG2C, dc, rc[k].w + cc.w);
                float K   = __builtin_amdgcn_exp2f(arg);
                float du  = ru[k].x * cu.x + ru[k].y * cu.y + ru[k].z * cu.z;
                av[k] = fmaf(K * du * du, wj, av[k]);
            }
        }
    }

    float thr = av[0] * ru[0].w + av[1] * ru[1].w + av[2] * ru[2].w + av[3] * ru[3].w;
    thr *= 2.0f;
    for (int off = 32; off; off >>= 1) thr += __shfl_down(thr, off);
    if (lane == 0)
        atomicAdd(&acc[b * WS_STRIDE], thr);
}

__global__ void final_kernel(const float* __restrict__ acc, float* __restrict__ outv)
{
    float s = 0.f;
    for (int b = 0; b < B_CNT; ++b) s += acc[b * WS_STRIDE];
    outv[0] = 0.125f * s;
}

extern "C" void kernel_launch(void* const* d_in, const int* in_sizes, int n_in,
                              void* d_out, int out_size, void* d_ws, size_t ws_size,
                              hipStream_t stream)
{
    const float* outp = (const float*)d_in[0];  // (8,2000,3) f32
    const float* tgtp = (const float*)d_in[1];  // (8,2000,3) f32
    const float* tmpl = (const float*)d_in[3];  // (2000,3) f32
    float* acc = (float*)d_ws;                                   // 1 KiB
    float4* ecu = (float4*)((char*)d_ws + 1024);                 // 1 MiB edge data

    hipMemsetAsync(d_ws, 0, B_CNT * WS_STRIDE * sizeof(float), stream);
    pre_kernel<<<B_CNT * 16, 256, 0, stream>>>(outp, tgtp, tmpl, ecu, acc);
    pair_kernel<<<B_CNT * BLOCKS_PER_B, 64, 0, stream>>>(ecu, acc);
    final_kernel<<<1, 1, 0, stream>>>(acc, (float*)d_out);
}